// Round 10
// baseline (2466.119 us; speedup 1.0000x reference)
//
#include <hip/hip_runtime.h>

// ---------------- problem constants ----------------
#define T_TOK 4096      // B*S tokens
#define HDIM  2880
#define IDIM  2880
#define NEXP  8
#define TOPK  4
#define WEL   (2880 * 2880)   // elems per weight matrix

// Byte-minimized GEMM geometry at proven 2-blocks/CU concurrency (r8 pipeline):
//  - BM=256, BK=32, 512 thr (8 waves, 4M x 2N); gateup BN=96 (x2 mats), down BN=192
//  - tile LDS 28KB -> dbuf 56KB -> 2 blocks/CU; per-wave acc 96 VGPR (launch_bounds 512,4)
//  - DMA bytes: gateup ~4.9GB (-30% vs r8), down -50%
//  - LDS rows = 64B (4x16B granules), XOR swizzle: phys_granule = log_granule ^ (row&3)
//    (per-lane pre-swizzled GLOBAL source; both-sides involution as r3-r8)
//  - counted vmcnt gate per K-step (wave-dependent 4/3), raw s_barrier, dbuf
#define BM 256
#define BN_GU 96
#define BN_DN 192
#define BK 32
#define NPAN_GU 30      // 2880/96
#define NPAN_DN 15      // 2880/192
#define ASZ (BM * BK)        // 8192 elems / 16KB per buffer
#define BSZ_GU (BN_GU * BK)  // 3072 elems / 6KB
#define BSZ_DN (BN_DN * BK)  // 6144 elems / 12KB
#define NSTEP 90             // 2880/32

typedef __attribute__((ext_vector_type(8))) short  s16x8;
typedef __attribute__((ext_vector_type(8))) unsigned short u16x8;
typedef __attribute__((ext_vector_type(4))) float  f32x4;

__device__ __forceinline__ unsigned short f2bf(float f) {
  unsigned int u = __float_as_uint(f);
  u += 0x7FFFu + ((u >> 16) & 1u);
  return (unsigned short)(u >> 16);
}

__device__ __forceinline__ void gload16(const unsigned short* g, unsigned short* l) {
  __builtin_amdgcn_global_load_lds(
      (const __attribute__((address_space(1))) void*)g,
      (__attribute__((address_space(3))) void*)l, 16, 0, 0);
}

// bijective XCD-aware block swizzle (m204) over live count n
__device__ __forceinline__ int xcd_swz(int orig, int n) {
  int q = n >> 3, r = n & 7;
  int x = orig & 7, idx = orig >> 3;
  return (x < r ? x * (q + 1) : r * (q + 1) + (x - r) * q) + idx;
}

// ---------------- x f32 -> bf16 ----------------
__global__ __launch_bounds__(256) void cvt_kernel(const float* __restrict__ x,
                                                  unsigned short* __restrict__ xb) {
  int i = blockIdx.x * 256 + threadIdx.x;
  const f32x4* p = (const f32x4*)x;
  f32x4 a = p[2 * (size_t)i];
  f32x4 b = p[2 * (size_t)i + 1];
  u16x8 o;
  o[0] = f2bf(a[0]); o[1] = f2bf(a[1]); o[2] = f2bf(a[2]); o[3] = f2bf(a[3]);
  o[4] = f2bf(b[0]); o[5] = f2bf(b[1]); o[6] = f2bf(b[2]); o[7] = f2bf(b[3]);
  *(u16x8*)(xb + (size_t)i * 8) = o;
}

// ---------------- weight transpose+convert for a group of G experts ----------------
__global__ __launch_bounds__(256) void transpose_group_kernel(
    const float* __restrict__ wg, const float* __restrict__ wu,
    const float* __restrict__ wd, unsigned short* __restrict__ wbuf, int ge) {
  __shared__ unsigned short st[64][72];
  const int z = blockIdx.z, j = z / 3, m = z % 3;
  const float* src = (m == 0 ? wg : (m == 1 ? wu : wd)) + (size_t)(ge + j) * WEL;
  unsigned short* dst = wbuf + (size_t)(j * 3 + m) * WEL;
  const int k0 = blockIdx.x * 64, n0 = blockIdx.y * 64;
  const int tid = threadIdx.x;
#pragma unroll
  for (int u = 0; u < 4; ++u) {
    int idx = tid + u * 256;
    int kr = idx >> 4;
    int nc = (idx & 15) * 4;
    f32x4 v = *(const f32x4*)(src + (size_t)(k0 + kr) * 2880 + (n0 + nc));
#pragma unroll
    for (int q = 0; q < 4; ++q) st[nc + q][kr] = f2bf(v[q]);
  }
  __syncthreads();
  int n = tid >> 2;
  int kc = (tid & 3) * 16;
  u16x8 a = *(const u16x8*)(&st[n][kc]);
  u16x8 b = *(const u16x8*)(&st[n][kc + 8]);
  unsigned short* po = dst + (size_t)(n0 + n) * 2880 + (k0 + kc);
  *(u16x8*)(po) = a;
  *(u16x8*)(po + 8) = b;
}

// ---------------- router: 4 tokens/wave, butterfly reduce ----------------
__global__ __launch_bounds__(256) void router_kernel(const float* __restrict__ x,
                                                     const float* __restrict__ rw,
                                                     const float* __restrict__ rb,
                                                     float* __restrict__ aff,
                                                     int* __restrict__ cnt,
                                                     int* __restrict__ lst) {
  const int wv = threadIdx.x >> 6, lane = threadIdx.x & 63;
  const int tok0 = (blockIdx.x * 4 + wv) * 4;
  float acc[4][NEXP];
#pragma unroll
  for (int t = 0; t < 4; ++t)
#pragma unroll
    for (int e = 0; e < NEXP; ++e) acc[t][e] = 0.f;

#pragma unroll
  for (int it = 0; it < 12; ++it) {
    int c = it * 64 + lane;
    if (c < 720) {
      f32x4 w4[NEXP];
#pragma unroll
      for (int e = 0; e < NEXP; ++e)
        w4[e] = *(const f32x4*)(rw + (size_t)e * HDIM + c * 4);
#pragma unroll
      for (int t = 0; t < 4; ++t) {
        f32x4 xv = *(const f32x4*)(x + (size_t)(tok0 + t) * HDIM + c * 4);
#pragma unroll
        for (int e = 0; e < NEXP; ++e)
          acc[t][e] += xv[0] * w4[e][0] + xv[1] * w4[e][1] + xv[2] * w4[e][2] + xv[3] * w4[e][3];
      }
    }
  }
#pragma unroll
  for (int t = 0; t < 4; ++t)
#pragma unroll
    for (int e = 0; e < NEXP; ++e) {
#pragma unroll
      for (int m = 32; m; m >>= 1) acc[t][e] += __shfl_xor(acc[t][e], m);
    }
  if (lane < 4) {
    int tok = tok0 + lane;
    float lg[NEXP];
#pragma unroll
    for (int e = 0; e < NEXP; ++e) lg[e] = acc[lane][e] + rb[e];
    bool used[NEXP];
#pragma unroll
    for (int e = 0; e < NEXP; ++e) used[e] = false;
    int bi[TOPK]; float bv[TOPK];
#pragma unroll
    for (int s = 0; s < TOPK; ++s) {
      int best = 0; float vbest = -1e30f;
#pragma unroll
      for (int e = 0; e < NEXP; ++e)
        if (!used[e] && lg[e] > vbest) { vbest = lg[e]; best = e; }
      used[best] = true; bi[s] = best; bv[s] = vbest;
    }
    float mx = bv[0];
    float w[TOPK]; float ssum = 0.f;
#pragma unroll
    for (int s = 0; s < TOPK; ++s) { w[s] = __expf(bv[s] - mx); ssum += w[s]; }
    float o[NEXP];
#pragma unroll
    for (int e = 0; e < NEXP; ++e) o[e] = 0.f;
#pragma unroll
    for (int s = 0; s < TOPK; ++s) o[bi[s]] = w[s] / ssum;
#pragma unroll
    for (int e = 0; e < NEXP; ++e) aff[(size_t)tok * NEXP + e] = o[e];
#pragma unroll
    for (int s = 0; s < TOPK; ++s) {
      int p = atomicAdd(&cnt[bi[s]], 1);
      lst[bi[s] * T_TOK + p] = tok;
    }
  }
}

// ---------------- sched: per-expert block prefixes (gu/dn) + slot prefixes ----------------
__global__ void sched_kernel(const int* __restrict__ cnt, int* __restrict__ gbs_gu,
                             int* __restrict__ gbs_dn, int* __restrict__ ess,
                             int* __restrict__ gtot_gu, int* __restrict__ gtot_dn, int G) {
  if (threadIdx.x == 0 && blockIdx.x == 0) {
    int ng = NEXP / G;
    for (int g = 0; g < ng; ++g) {
      int bg_ = 0, bd_ = 0, s = 0;
      for (int j = 0; j < G; ++j) {
        int e = g * G + j;
        gbs_gu[e] = bg_; gbs_dn[e] = bd_; ess[e] = s;
        int mb = (cnt[e] + BM - 1) / BM;
        bg_ += mb * NPAN_GU;
        bd_ += mb * NPAN_DN;
        s += cnt[e];
      }
      gtot_gu[g] = bg_; gtot_dn[g] = bd_;
    }
  }
}

// ---------------- gate/up fused GEMM + SwiGLU + affinity -> h4 ----------
__global__ __launch_bounds__(512, 4) void gateup_kernel(
    const unsigned short* __restrict__ xb, const unsigned short* __restrict__ wbuf,
    const float* __restrict__ aff, const int* __restrict__ lst,
    const int* __restrict__ cnts, const int* __restrict__ gbs,
    const int* __restrict__ ess, const int* __restrict__ gtot_g,
    unsigned short* __restrict__ h4, int ge, int G) {
  const int gt = *gtot_g;
  if ((int)blockIdx.x >= gt) return;
  const int bx = xcd_swz(blockIdx.x, gt);
  int j = 0;
  for (int t = 1; t < G; ++t) j += (bx >= gbs[ge + t]) ? 1 : 0;
  const int e = ge + j;
  const int cnt = cnts[e];
  const int mb = (cnt + BM - 1) >> 8;
  const int local = bx - gbs[e];
  const int nIdx = local / mb;
  const int m0 = (local - nIdx * mb) * BM;
  const int n0 = nIdx * BN_GU;
  const int slotbase = ess[e];
  const unsigned short* wgt = wbuf + (size_t)j * 3 * WEL;
  const unsigned short* wut = wgt + WEL;

  __shared__ __align__(16) unsigned short Al[2 * ASZ];      // 32KB
  __shared__ __align__(16) unsigned short Bgl[2 * BSZ_GU];  // 12KB
  __shared__ __align__(16) unsigned short Bul[2 * BSZ_GU];  // 12KB

  const int tid = threadIdx.x;
  const int wv = tid >> 6, lane = tid & 63;
  const int msub = (wv >> 1) * 64, nsub = (wv & 1) * 48;
  const int l15 = lane & 15, l4 = lane >> 4;
  const int lr4 = lane >> 2, lg = lane & 3;   // staging: row-in-seg, granule
  const int* mylst = lst + e * T_TOK;

  // A: 16 segs (16 rows x 64B); wave wv stages segs {wv, 8+wv}
  const unsigned short* asrc[2]; unsigned short* adst[2];
#pragma unroll
  for (int u = 0; u < 2; ++u) {
    int s = wv + 8 * u;
    int r = s * 16 + lr4;
    int tok = mylst[min(m0 + r, cnt - 1)];
    asrc[u] = xb + (size_t)tok * HDIM + (lg ^ (r & 3)) * 8;
    adst[u] = &Al[s * 512];
  }
  // Bg: 6 segs -> waves 0-5; Bu: 6 segs -> waves 2-7
  const bool hasg = (wv < 6), hasu = (wv >= 2);
  const unsigned short* bgsrc = nullptr; unsigned short* bgdst = nullptr;
  const unsigned short* busrc = nullptr; unsigned short* budst = nullptr;
  if (hasg) {
    int r = wv * 16 + lr4;
    bgsrc = wgt + (size_t)(n0 + r) * HDIM + (size_t)((lg ^ (r & 3)) * 8);
    bgdst = &Bgl[wv * 512];
  }
  if (hasu) {
    int s = wv - 2;
    int r = s * 16 + lr4;
    busrc = wut + (size_t)(n0 + r) * HDIM + (size_t)((lg ^ (r & 3)) * 8);
    budst = &Bul[s * 512];
  }

  f32x4 accg[4][3]; f32x4 accu[4][3];
#pragma unroll
  for (int mf = 0; mf < 4; ++mf)
#pragma unroll
    for (int nf = 0; nf < 3; ++nf) { accg[mf][nf] = (f32x4)0.f; accu[mf][nf] = (f32x4)0.f; }

  auto stage = [&](int buf, int k0) {   // 3 or 4 VMEM ops per wave
    int ao = buf * ASZ, bo = buf * BSZ_GU;
    gload16(asrc[0] + k0, adst[0] + ao);
    gload16(asrc[1] + k0, adst[1] + ao);
    if (hasg) gload16(bgsrc + k0, bgdst + bo);
    if (hasu) gload16(busrc + k0, budst + bo);
  };
  auto gate = [&]() {   // wait: previous tile's own-wave loads done
    if (wv >= 2 && wv < 6) { asm volatile("s_waitcnt vmcnt(4)" ::: "memory"); }
    else                   { asm volatile("s_waitcnt vmcnt(3)" ::: "memory"); }
  };
  auto compute = [&](int buf) {
    const unsigned short* Ab = Al + buf * ASZ;
    const unsigned short* Bg = Bgl + buf * BSZ_GU;
    const unsigned short* Bu = Bul + buf * BSZ_GU;
    s16x8 af[4];
#pragma unroll
    for (int mf = 0; mf < 4; ++mf) {
      int R = msub + mf * 16 + l15;
      af[mf] = *(const s16x8*)(&Ab[R * 32 + (l4 ^ (R & 3)) * 8]);
    }
#pragma unroll
    for (int nf = 0; nf < 3; ++nf) {
      int R = nsub + nf * 16 + l15;
      int so = R * 32 + (l4 ^ (R & 3)) * 8;
      s16x8 bg = *(const s16x8*)(&Bg[so]);
      s16x8 bu = *(const s16x8*)(&Bu[so]);
#pragma unroll
      for (int mf = 0; mf < 4; ++mf) {
        accg[mf][nf] = __builtin_amdgcn_mfma_f32_16x16x32_bf16(af[mf], bg, accg[mf][nf], 0, 0, 0);
        accu[mf][nf] = __builtin_amdgcn_mfma_f32_16x16x32_bf16(af[mf], bu, accu[mf][nf], 0, 0, 0);
      }
    }
  };

  // dbuf counted-vmcnt pipeline, NSTEP even
  stage(0, 0);
#pragma unroll 1
  for (int t = 0; t < NSTEP - 2; t += 2) {
    stage(1, (t + 1) * BK);
    gate();
    __builtin_amdgcn_s_barrier();
    compute(0);
    __builtin_amdgcn_s_barrier();
    stage(0, (t + 2) * BK);
    gate();
    __builtin_amdgcn_s_barrier();
    compute(1);
    __builtin_amdgcn_s_barrier();
  }
  stage(1, (NSTEP - 1) * BK);
  gate();
  __builtin_amdgcn_s_barrier();
  compute(0);                       // tile NSTEP-2
  __builtin_amdgcn_s_barrier();
  asm volatile("s_waitcnt vmcnt(0)" ::: "memory");
  __builtin_amdgcn_s_barrier();
  compute(1);                       // tile NSTEP-1

  // epilogue: h4[slot] = aff * silu(g) * u
#pragma unroll
  for (int mf = 0; mf < 4; ++mf)
#pragma unroll
    for (int r = 0; r < 4; ++r) {
      int slot = m0 + msub + mf * 16 + l4 * 4 + r;
      if (slot < cnt) {
        int tok = mylst[slot];
        float av = aff[(size_t)tok * NEXP + e];
#pragma unroll
        for (int nf = 0; nf < 3; ++nf) {
          float g = accg[mf][nf][r], uu = accu[mf][nf][r];
          float hv = (g / (1.f + __expf(-g))) * uu * av;
          int col = n0 + nsub + nf * 16 + l15;
          h4[(size_t)(slotbase + slot) * IDIM + col] = f2bf(hv);
        }
      }
    }
}

// ---------------- down GEMM: out[tok] += h4[slot] @ WdT (atomic combine) ----------------
__global__ __launch_bounds__(512, 4) void down_kernel(
    const unsigned short* __restrict__ h4, const unsigned short* __restrict__ wbuf,
    float* __restrict__ out, const int* __restrict__ lst,
    const int* __restrict__ cnts, const int* __restrict__ gbs,
    const int* __restrict__ ess, const int* __restrict__ gtot_g,
    int ge, int G) {
  const int gt = *gtot_g;
  if ((int)blockIdx.x >= gt) return;
  const int bx = xcd_swz(blockIdx.x, gt);
  int j = 0;
  for (int t = 1; t < G; ++t) j += (bx >= gbs[ge + t]) ? 1 : 0;
  const int e = ge + j;
  const int cnt = cnts[e];
  const int mb = (cnt + BM - 1) >> 8;
  const int local = bx - gbs[e];
  const int nIdx = local / mb;
  const int m0 = (local - nIdx * mb) * BM;
  const int n0 = nIdx * BN_DN;
  const int slotbase = ess[e];
  const unsigned short* wdt = wbuf + (size_t)j * 3 * WEL + 2 * (size_t)WEL;

  __shared__ __align__(16) unsigned short Al[2 * ASZ];      // 32KB
  __shared__ __align__(16) unsigned short Bl[2 * BSZ_DN];   // 24KB

  const int tid = threadIdx.x;
  const int wv = tid >> 6, lane = tid & 63;
  const int msub = (wv >> 1) * 64, nsub = (wv & 1) * 96;
  const int l15 = lane & 15, l4 = lane >> 4;
  const int lr4 = lane >> 2, lg = lane & 3;
  const int* mylst = lst + e * T_TOK;

  const unsigned short* asrc[2]; unsigned short* adst[2];
#pragma unroll
  for (int u = 0; u < 2; ++u) {
    int s = wv + 8 * u;
    int r = s * 16 + lr4;
    int hr = min(m0 + r, cnt - 1);
    asrc[u] = h4 + (size_t)(slotbase + hr) * IDIM + (lg ^ (r & 3)) * 8;
    adst[u] = &Al[s * 512];
  }
  // B: 12 segs; all waves seg wv; waves 0-3 also seg 8+wv
  const bool hasb1 = (wv < 4);
  const unsigned short* bsrc0; unsigned short* bdst0;
  const unsigned short* bsrc1 = nullptr; unsigned short* bdst1 = nullptr;
  {
    int r0 = wv * 16 + lr4;
    bsrc0 = wdt + (size_t)(n0 + r0) * IDIM + (size_t)((lg ^ (r0 & 3)) * 8);
    bdst0 = &Bl[wv * 512];
    if (hasb1) {
      int s1 = 8 + wv;
      int r1 = s1 * 16 + lr4;
      bsrc1 = wdt + (size_t)(n0 + r1) * IDIM + (size_t)((lg ^ (r1 & 3)) * 8);
      bdst1 = &Bl[s1 * 512];
    }
  }

  f32x4 acc[4][6];
#pragma unroll
  for (int mf = 0; mf < 4; ++mf)
#pragma unroll
    for (int nf = 0; nf < 6; ++nf) acc[mf][nf] = (f32x4)0.f;

  auto stage = [&](int buf, int k0) {   // 3 or 4 VMEM ops per wave
    int ao = buf * ASZ, bo = buf * BSZ_DN;
    gload16(asrc[0] + k0, adst[0] + ao);
    gload16(asrc[1] + k0, adst[1] + ao);
    gload16(bsrc0 + k0, bdst0 + bo);
    if (hasb1) gload16(bsrc1 + k0, bdst1 + bo);
  };
  auto gate = [&]() {
    if (wv < 4) { asm volatile("s_waitcnt vmcnt(4)" ::: "memory"); }
    else        { asm volatile("s_waitcnt vmcnt(3)" ::: "memory"); }
  };
  auto compute = [&](int buf) {
    const unsigned short* Ab = Al + buf * ASZ;
    const unsigned short* Bb = Bl + buf * BSZ_DN;
    s16x8 af[4];
#pragma unroll
    for (int mf = 0; mf < 4; ++mf) {
      int R = msub + mf * 16 + l15;
      af[mf] = *(const s16x8*)(&Ab[R * 32 + (l4 ^ (R & 3)) * 8]);
    }
#pragma unroll
    for (int nf = 0; nf < 6; ++nf) {
      int R = nsub + nf * 16 + l15;
      s16x8 b = *(const s16x8*)(&Bb[R * 32 + (l4 ^ (R & 3)) * 8]);
#pragma unroll
      for (int mf = 0; mf < 4; ++mf)
        acc[mf][nf] = __builtin_amdgcn_mfma_f32_16x16x32_bf16(af[mf], b, acc[mf][nf], 0, 0, 0);
    }
  };

  stage(0, 0);
#pragma unroll 1
  for (int t = 0; t < NSTEP - 2; t += 2) {
    stage(1, (t + 1) * BK);
    gate();
    __builtin_amdgcn_s_barrier();
    compute(0);
    __builtin_amdgcn_s_barrier();
    stage(0, (t + 2) * BK);
    gate();
    __builtin_amdgcn_s_barrier();
    compute(1);
    __builtin_amdgcn_s_barrier();
  }
  stage(1, (NSTEP - 1) * BK);
  gate();
  __builtin_amdgcn_s_barrier();
  compute(0);
  __builtin_amdgcn_s_barrier();
  asm volatile("s_waitcnt vmcnt(0)" ::: "memory");
  __builtin_amdgcn_s_barrier();
  compute(1);

#pragma unroll
  for (int mf = 0; mf < 4; ++mf)
#pragma unroll
    for (int r = 0; r < 4; ++r) {
      int slot = m0 + msub + mf * 16 + l4 * 4 + r;
      if (slot < cnt) {
        int tok = mylst[slot];
#pragma unroll
        for (int nf = 0; nf < 6; ++nf) {
          int col = n0 + nsub + nf * 16 + l15;
          atomicAdd(out + (size_t)tok * HDIM + col, acc[mf][nf][r]);
        }
      }
    }
}

// ---------------- launcher ----------------
extern "C" void kernel_launch(void* const* d_in, const int* in_sizes, int n_in,
                              void* d_out, int out_size, void* d_ws, size_t ws_size,
                              hipStream_t stream) {
  (void)in_sizes; (void)n_in;
  const float* x  = (const float*)d_in[0];
  const float* rw = (const float*)d_in[1];
  const float* rb = (const float*)d_in[2];
  const float* wg = (const float*)d_in[3];
  const float* wu = (const float*)d_in[4];
  const float* wd = (const float*)d_in[5];
  float* out = (float*)d_out;

  char* ws = (char*)d_ws;
  float* aff     = (float*)ws;                     // 131072 B
  int*   cnt     = (int*)(ws + 131072);            // 512 B
  int*   lst     = (int*)(ws + 131584);            // 131072 B
  int*   gbs_gu  = (int*)(ws + 262656);            // 64 B
  int*   gbs_dn  = (int*)(ws + 262720);            // 64 B
  int*   ess     = (int*)(ws + 262784);            // 64 B
  int*   gtot_gu = (int*)(ws + 262848);            // 64 B
  int*   gtot_dn = (int*)(ws + 262912);            // 64 B
  unsigned short* xb = (unsigned short*)(ws + 263168);   // 23,592,960 B
  const size_t OFF_H4 = 263168 + 23592960ull;

  const size_t WELB = (size_t)WEL * 2;
  int G = 1;
  {
    size_t need8 = OFF_H4 + (size_t)16384 * IDIM * 2 + 8 * 3 * WELB;
    size_t need2 = OFF_H4 + (size_t)8192  * IDIM * 2 + 2 * 3 * WELB;
    if (ws_size >= need8) G = 8;
    else if (ws_size >= need2) G = 2;
  }
  const size_t h4b = (size_t)((G == 8) ? 16384 : (G == 2 ? 8192 : 4096)) * IDIM * 2;
  unsigned short* h4   = (unsigned short*)(ws + OFF_H4);
  unsigned short* wbuf = (unsigned short*)(ws + OFF_H4 + h4b);

  const int NG = NEXP / G;
  const int NBLK_GU = (T_TOK * TOPK / BM + NEXP) * NPAN_GU;  // 72*30 = 2160
  const int NBLK_DN = (T_TOK * TOPK / BM + NEXP) * NPAN_DN;  // 72*15 = 1080

  hipMemsetAsync(out, 0, (size_t)out_size * sizeof(float), stream);
  hipMemsetAsync(cnt, 0, 512, stream);
  cvt_kernel<<<(T_TOK * HDIM / 8) / 256, 256, 0, stream>>>(x, xb);
  router_kernel<<<T_TOK / 16, 256, 0, stream>>>(x, rw, rb, aff, cnt, lst);
  sched_kernel<<<1, 64, 0, stream>>>(cnt, gbs_gu, gbs_dn, ess, gtot_gu, gtot_dn, G);

  for (int g = 0; g < NG; ++g) {
    int ge = g * G;
    transpose_group_kernel<<<dim3(45, 45, 3 * G), 256, 0, stream>>>(wg, wu, wd, wbuf, ge);
    gateup_kernel<<<NBLK_GU, 512, 0, stream>>>(
        xb, wbuf, aff, lst, cnt, gbs_gu, ess, gtot_gu + g, h4, ge, G);
    down_kernel<<<NBLK_DN, 512, 0, stream>>>(
        h4, wbuf, out, lst, cnt, gbs_dn, ess, gtot_dn + g, ge, G);
  }
}

// Round 11
// 1233.057 us; speedup vs baseline: 2.0000x; 2.0000x over previous
//
#include <hip/hip_runtime.h>

// ---------------- problem constants ----------------
#define T_TOK 4096      // B*S tokens
#define HDIM  2880
#define IDIM  2880
#define NEXP  8
#define TOPK  4
#define WEL   (2880 * 2880)   // elems per weight matrix

// Supply model (r5-r10 measured): 2-phase + counted-vmcnt @ 2 blocks/CU sustains
// ~10.8 TB/s DMA; kernel rate = 10.8 TB/s x intensity(FLOP/B).
//  - gateup: BM=128, BN=96 x {gate,up} -> 77 FLOP/B (r8-proven, 650us)
//  - down:   BM=128, BN=192            -> 77 FLOP/B (was 55 at BN=96)
// LDS tiles LINEAR [row][64] bf16 (128B rows), XOR swizzle on 16B k-slot:
//   phys_slot = log_slot ^ (row & 7); per-lane GLOBAL source pre-swizzled
// dbuf + raw s_barrier + counted vmcnt(10); 80KB LDS -> 2 blocks/CU.
#define BM 128
#define BN_GU 96
#define BN_DN 192
#define BK 64
#define NPAN_GU 30      // 2880/96
#define NPAN_DN 15      // 2880/192
#define ASZ (BM * BK)        // 8192 elems / 16KB per buffer half
#define BSZ_GU (BN_GU * BK)  // 6144 elems / 12KB
#define BSZ_DN (BN_DN * BK)  // 12288 elems / 24KB
#define NSTEP 45             // 2880/64

typedef __attribute__((ext_vector_type(8))) short  s16x8;
typedef __attribute__((ext_vector_type(8))) unsigned short u16x8;
typedef __attribute__((ext_vector_type(4))) unsigned short u16x4;
typedef __attribute__((ext_vector_type(4))) float  f32x4;

__device__ __forceinline__ unsigned short f2bf(float f) {
  unsigned int u = __float_as_uint(f);
  u += 0x7FFFu + ((u >> 16) & 1u);
  return (unsigned short)(u >> 16);
}

__device__ __forceinline__ void gload16(const unsigned short* g, unsigned short* l) {
  __builtin_amdgcn_global_load_lds(
      (const __attribute__((address_space(1))) void*)g,
      (__attribute__((address_space(3))) void*)l, 16, 0, 0);
}

// bijective XCD-aware block swizzle (m204) over live count n
__device__ __forceinline__ int xcd_swz(int orig, int n) {
  int q = n >> 3, r = n & 7;
  int x = orig & 7, idx = orig >> 3;
  return (x < r ? x * (q + 1) : r * (q + 1) + (x - r) * q) + idx;
}

// ---------------- weight transpose+convert for a group of G experts ----------------
__global__ __launch_bounds__(256) void transpose_group_kernel(
    const float* __restrict__ wg, const float* __restrict__ wu,
    const float* __restrict__ wd, unsigned short* __restrict__ wbuf, int ge) {
  __shared__ unsigned short st[64][72];
  const int z = blockIdx.z, j = z / 3, m = z % 3;
  const float* src = (m == 0 ? wg : (m == 1 ? wu : wd)) + (size_t)(ge + j) * WEL;
  unsigned short* dst = wbuf + (size_t)(j * 3 + m) * WEL;
  const int k0 = blockIdx.x * 64, n0 = blockIdx.y * 64;
  const int tid = threadIdx.x;
#pragma unroll
  for (int u = 0; u < 4; ++u) {
    int idx = tid + u * 256;
    int kr = idx >> 4;
    int nc = (idx & 15) * 4;
    f32x4 v = *(const f32x4*)(src + (size_t)(k0 + kr) * 2880 + (n0 + nc));
#pragma unroll
    for (int q = 0; q < 4; ++q) st[nc + q][kr] = f2bf(v[q]);
  }
  __syncthreads();
  int n = tid >> 2;
  int kc = (tid & 3) * 16;
  u16x8 a = *(const u16x8*)(&st[n][kc]);
  u16x8 b = *(const u16x8*)(&st[n][kc + 8]);
  unsigned short* po = dst + (size_t)(n0 + n) * 2880 + (k0 + kc);
  *(u16x8*)(po) = a;
  *(u16x8*)(po + 8) = b;
}

// ---------------- router (+fused x->bf16 cvt): 4 tokens/wave ----------------
__global__ __launch_bounds__(256) void router_kernel(const float* __restrict__ x,
                                                     const float* __restrict__ rw,
                                                     const float* __restrict__ rb,
                                                     float* __restrict__ aff,
                                                     int* __restrict__ cnt,
                                                     int* __restrict__ lst,
                                                     unsigned short* __restrict__ xb) {
  const int wv = threadIdx.x >> 6, lane = threadIdx.x & 63;
  const int tok0 = (blockIdx.x * 4 + wv) * 4;
  float acc[4][NEXP];
#pragma unroll
  for (int t = 0; t < 4; ++t)
#pragma unroll
    for (int e = 0; e < NEXP; ++e) acc[t][e] = 0.f;

#pragma unroll
  for (int it = 0; it < 12; ++it) {
    int c = it * 64 + lane;
    if (c < 720) {
      f32x4 w4[NEXP];
#pragma unroll
      for (int e = 0; e < NEXP; ++e)
        w4[e] = *(const f32x4*)(rw + (size_t)e * HDIM + c * 4);
#pragma unroll
      for (int t = 0; t < 4; ++t) {
        f32x4 xv = *(const f32x4*)(x + (size_t)(tok0 + t) * HDIM + c * 4);
        // fused cvt: write bf16 copy of x
        u16x4 o;
        o[0] = f2bf(xv[0]); o[1] = f2bf(xv[1]); o[2] = f2bf(xv[2]); o[3] = f2bf(xv[3]);
        *(u16x4*)(xb + (size_t)(tok0 + t) * HDIM + c * 4) = o;
#pragma unroll
        for (int e = 0; e < NEXP; ++e)
          acc[t][e] += xv[0] * w4[e][0] + xv[1] * w4[e][1] + xv[2] * w4[e][2] + xv[3] * w4[e][3];
      }
    }
  }
#pragma unroll
  for (int t = 0; t < 4; ++t)
#pragma unroll
    for (int e = 0; e < NEXP; ++e) {
#pragma unroll
      for (int m = 32; m; m >>= 1) acc[t][e] += __shfl_xor(acc[t][e], m);
    }
  if (lane < 4) {
    int tok = tok0 + lane;
    float lg[NEXP];
#pragma unroll
    for (int e = 0; e < NEXP; ++e) lg[e] = acc[lane][e] + rb[e];
    bool used[NEXP];
#pragma unroll
    for (int e = 0; e < NEXP; ++e) used[e] = false;
    int bi[TOPK]; float bv[TOPK];
#pragma unroll
    for (int s = 0; s < TOPK; ++s) {
      int best = 0; float vbest = -1e30f;
#pragma unroll
      for (int e = 0; e < NEXP; ++e)
        if (!used[e] && lg[e] > vbest) { vbest = lg[e]; best = e; }
      used[best] = true; bi[s] = best; bv[s] = vbest;
    }
    float mx = bv[0];
    float w[TOPK]; float ssum = 0.f;
#pragma unroll
    for (int s = 0; s < TOPK; ++s) { w[s] = __expf(bv[s] - mx); ssum += w[s]; }
    float o[NEXP];
#pragma unroll
    for (int e = 0; e < NEXP; ++e) o[e] = 0.f;
#pragma unroll
    for (int s = 0; s < TOPK; ++s) o[bi[s]] = w[s] / ssum;
#pragma unroll
    for (int e = 0; e < NEXP; ++e) aff[(size_t)tok * NEXP + e] = o[e];
#pragma unroll
    for (int s = 0; s < TOPK; ++s) {
      int p = atomicAdd(&cnt[bi[s]], 1);
      lst[bi[s] * T_TOK + p] = tok;
    }
  }
}

// ---------------- sched: per-expert block prefixes (gu/dn) + slot prefixes ----------------
__global__ void sched_kernel(const int* __restrict__ cnt, int* __restrict__ gbs_gu,
                             int* __restrict__ gbs_dn, int* __restrict__ ess,
                             int* __restrict__ gtot_gu, int* __restrict__ gtot_dn, int G) {
  if (threadIdx.x == 0 && blockIdx.x == 0) {
    int ng = NEXP / G;
    for (int g = 0; g < ng; ++g) {
      int bg_ = 0, bd_ = 0, s = 0;
      for (int j = 0; j < G; ++j) {
        int e = g * G + j;
        gbs_gu[e] = bg_; gbs_dn[e] = bd_; ess[e] = s;
        int mb = (cnt[e] + BM - 1) / BM;
        bg_ += mb * NPAN_GU;
        bd_ += mb * NPAN_DN;
        s += cnt[e];
      }
      gtot_gu[g] = bg_; gtot_dn[g] = bd_;
    }
  }
}

// locate (expert, m0, nIdx) from live-swizzled block id; expert-major, n-outer, m-inner
__device__ __forceinline__ bool locate(int orig, const int* gbs, const int* cnts,
                                       int ge, int G, const int* gtot_g,
                                       int& e, int& m0, int& nIdx, int& cnt) {
  int gt = *gtot_g;
  if (orig >= gt) return false;
  int bx = xcd_swz(orig, gt);
  int j = 0;
  for (int t = 1; t < G; ++t) j += (bx >= gbs[ge + t]) ? 1 : 0;
  e = ge + j;
  cnt = cnts[e];
  int mb = (cnt + BM - 1) >> 7;
  int local = bx - gbs[e];
  nIdx = local / mb;
  m0 = (local - nIdx * mb) * BM;
  return true;
}

// ---------------- gate/up fused GEMM + SwiGLU + affinity -> h4 (r8-proven) ----------
__global__ __launch_bounds__(256) void gateup_kernel(
    const unsigned short* __restrict__ xb, const unsigned short* __restrict__ wbuf,
    const float* __restrict__ aff, const int* __restrict__ lst,
    const int* __restrict__ cnts, const int* __restrict__ gbs,
    const int* __restrict__ ess, const int* __restrict__ gtot_g,
    unsigned short* __restrict__ h4, int ge, int G) {
  int e, m0, nIdx, cnt;
  if (!locate(blockIdx.x, gbs, cnts, ge, G, gtot_g, e, m0, nIdx, cnt)) return;
  const int n0 = nIdx * BN_GU;
  const int j = e - ge;
  const int slotbase = ess[e];
  const unsigned short* wgt = wbuf + (size_t)j * 3 * WEL;
  const unsigned short* wut = wgt + WEL;

  __shared__ __align__(16) unsigned short Al[2 * ASZ];     // 32KB dbuf
  __shared__ __align__(16) unsigned short Bgl[2 * BSZ_GU]; // 24KB
  __shared__ __align__(16) unsigned short Bul[2 * BSZ_GU]; // 24KB

  const int tid = threadIdx.x;
  const int wv = tid >> 6, lane = tid & 63;
  const int msub = (wv >> 1) * 64, nsub = (wv & 1) * 48;
  const int l15 = lane & 15, l4 = lane >> 4;
  const int lr = lane >> 3, lc = lane & 7;
  const int* mylst = lst + e * T_TOK;

  const unsigned short* asrc[4]; unsigned short* adst[4];
#pragma unroll
  for (int u = 0; u < 4; ++u) {
    int s = u * 4 + wv;
    int r = s * 8 + lr;
    int tok = mylst[min(m0 + r, cnt - 1)];
    asrc[u] = xb + (size_t)tok * HDIM + (lc ^ (r & 7)) * 8;
    adst[u] = &Al[s * 512];
  }
  const unsigned short* bgsrc[3]; const unsigned short* busrc[3];
  unsigned short* bgdst[3]; unsigned short* budst[3];
#pragma unroll
  for (int u = 0; u < 3; ++u) {
    int s = u * 4 + wv;
    int r = s * 8 + lr;
    size_t off = (size_t)(n0 + r) * HDIM + (size_t)((lc ^ (r & 7)) * 8);
    bgsrc[u] = wgt + off; busrc[u] = wut + off;
    bgdst[u] = &Bgl[s * 512]; budst[u] = &Bul[s * 512];
  }

  f32x4 accg[4][3]; f32x4 accu[4][3];
#pragma unroll
  for (int mf = 0; mf < 4; ++mf)
#pragma unroll
    for (int nf = 0; nf < 3; ++nf) { accg[mf][nf] = (f32x4)0.f; accu[mf][nf] = (f32x4)0.f; }

  auto stage = [&](int buf, int k0) {   // 10 VMEM ops per wave
    int ao = buf * ASZ, bo = buf * BSZ_GU;
#pragma unroll
    for (int u = 0; u < 4; ++u) gload16(asrc[u] + k0, adst[u] + ao);
#pragma unroll
    for (int u = 0; u < 3; ++u) {
      gload16(bgsrc[u] + k0, bgdst[u] + bo);
      gload16(busrc[u] + k0, budst[u] + bo);
    }
  };
  auto compute = [&](int buf) {
    const unsigned short* Ab = Al + buf * ASZ;
    const unsigned short* Bg = Bgl + buf * BSZ_GU;
    const unsigned short* Bu = Bul + buf * BSZ_GU;
#pragma unroll
    for (int kk = 0; kk < 2; ++kk) {
      s16x8 af[4];
#pragma unroll
      for (int mf = 0; mf < 4; ++mf) {
        int R = msub + mf * 16 + l15;
        int sl = (kk * 4 + l4) ^ (R & 7);
        af[mf] = *(const s16x8*)(&Ab[R * 64 + sl * 8]);
      }
#pragma unroll
      for (int nf = 0; nf < 3; ++nf) {
        int R = nsub + nf * 16 + l15;
        int sl = (kk * 4 + l4) ^ (R & 7);
        s16x8 bg = *(const s16x8*)(&Bg[R * 64 + sl * 8]);
        s16x8 bu = *(const s16x8*)(&Bu[R * 64 + sl * 8]);
#pragma unroll
        for (int mf = 0; mf < 4; ++mf) {
          accg[mf][nf] = __builtin_amdgcn_mfma_f32_16x16x32_bf16(af[mf], bg, accg[mf][nf], 0, 0, 0);
          accu[mf][nf] = __builtin_amdgcn_mfma_f32_16x16x32_bf16(af[mf], bu, accu[mf][nf], 0, 0, 0);
        }
      }
    }
  };

  stage(0, 0);
#pragma unroll 1
  for (int t = 0; t < NSTEP - 1; t += 2) {
    stage(1, (t + 1) * BK);
    asm volatile("s_waitcnt vmcnt(10)" ::: "memory");
    __builtin_amdgcn_s_barrier();
    compute(0);
    __builtin_amdgcn_s_barrier();
    stage(0, (t + 2) * BK);
    asm volatile("s_waitcnt vmcnt(10)" ::: "memory");
    __builtin_amdgcn_s_barrier();
    compute(1);
    __builtin_amdgcn_s_barrier();
  }
  asm volatile("s_waitcnt vmcnt(0)" ::: "memory");
  __builtin_amdgcn_s_barrier();
  compute(0);   // tile 44 lives in buf 0

#pragma unroll
  for (int mf = 0; mf < 4; ++mf)
#pragma unroll
    for (int r = 0; r < 4; ++r) {
      int slot = m0 + msub + mf * 16 + l4 * 4 + r;
      if (slot < cnt) {
        int tok = mylst[slot];
        float av = aff[(size_t)tok * NEXP + e];
#pragma unroll
        for (int nf = 0; nf < 3; ++nf) {
          float g = accg[mf][nf][r], uu = accu[mf][nf][r];
          float hv = (g / (1.f + __expf(-g))) * uu * av;
          int col = n0 + nsub + nf * 16 + l15;
          h4[(size_t)(slotbase + slot) * IDIM + col] = f2bf(hv);
        }
      }
    }
}

// ---------------- down GEMM (BN=192): out[tok] += h4[slot] @ WdT ----------------
__global__ __launch_bounds__(256) void down_kernel(
    const unsigned short* __restrict__ h4, const unsigned short* __restrict__ wbuf,
    float* __restrict__ out, const int* __restrict__ lst,
    const int* __restrict__ cnts, const int* __restrict__ gbs,
    const int* __restrict__ ess, const int* __restrict__ gtot_g,
    int ge, int G) {
  int e, m0, nIdx, cnt;
  if (!locate(blockIdx.x, gbs, cnts, ge, G, gtot_g, e, m0, nIdx, cnt)) return;
  const int n0 = nIdx * BN_DN;
  const int j = e - ge;
  const int slotbase = ess[e];
  const unsigned short* wdt = wbuf + (size_t)j * 3 * WEL + 2 * (size_t)WEL;

  __shared__ __align__(16) unsigned short Al[2 * ASZ];     // 32KB
  __shared__ __align__(16) unsigned short Bl[2 * BSZ_DN];  // 48KB

  const int tid = threadIdx.x;
  const int wv = tid >> 6, lane = tid & 63;
  const int msub = (wv >> 1) * 64, nsub = (wv & 1) * 96;
  const int l15 = lane & 15, l4 = lane >> 4;
  const int lr = lane >> 3, lc = lane & 7;
  const int* mylst = lst + e * T_TOK;

  const unsigned short* asrc[4]; unsigned short* adst[4];
#pragma unroll
  for (int u = 0; u < 4; ++u) {
    int s = u * 4 + wv;
    int r = s * 8 + lr;
    int hr = min(m0 + r, cnt - 1);
    asrc[u] = h4 + (size_t)(slotbase + hr) * IDIM + (lc ^ (r & 7)) * 8;
    adst[u] = &Al[s * 512];
  }
  // B: 24 segs (192 rows), 6 per wave: s = u*4+wv, u=0..5
  const unsigned short* bsrc[6]; unsigned short* bdst[6];
#pragma unroll
  for (int u = 0; u < 6; ++u) {
    int s = u * 4 + wv;
    int r = s * 8 + lr;
    bsrc[u] = wdt + (size_t)(n0 + r) * IDIM + (size_t)((lc ^ (r & 7)) * 8);
    bdst[u] = &Bl[s * 512];
  }

  f32x4 acc[4][6];
#pragma unroll
  for (int mf = 0; mf < 4; ++mf)
#pragma unroll
    for (int nf = 0; nf < 6; ++nf) acc[mf][nf] = (f32x4)0.f;

  auto stage = [&](int buf, int k0) {   // 10 VMEM ops per wave
    int ao = buf * ASZ, bo = buf * BSZ_DN;
#pragma unroll
    for (int u = 0; u < 4; ++u) gload16(asrc[u] + k0, adst[u] + ao);
#pragma unroll
    for (int u = 0; u < 6; ++u) gload16(bsrc[u] + k0, bdst[u] + bo);
  };
  auto compute = [&](int buf) {
    const unsigned short* Ab = Al + buf * ASZ;
    const unsigned short* Bb = Bl + buf * BSZ_DN;
#pragma unroll
    for (int kk = 0; kk < 2; ++kk) {
      s16x8 af[4];
#pragma unroll
      for (int mf = 0; mf < 4; ++mf) {
        int R = msub + mf * 16 + l15;
        int sl = (kk * 4 + l4) ^ (R & 7);
        af[mf] = *(const s16x8*)(&Ab[R * 64 + sl * 8]);
      }
#pragma unroll
      for (int nf = 0; nf < 6; ++nf) {
        int R = nsub + nf * 16 + l15;
        int sl = (kk * 4 + l4) ^ (R & 7);
        s16x8 bb = *(const s16x8*)(&Bl[buf * BSZ_DN + R * 64 + sl * 8]);
#pragma unroll
        for (int mf = 0; mf < 4; ++mf)
          acc[mf][nf] = __builtin_amdgcn_mfma_f32_16x16x32_bf16(af[mf], bb, acc[mf][nf], 0, 0, 0);
      }
      (void)Bb;
    }
  };

  stage(0, 0);
#pragma unroll 1
  for (int t = 0; t < NSTEP - 1; t += 2) {
    stage(1, (t + 1) * BK);
    asm volatile("s_waitcnt vmcnt(10)" ::: "memory");
    __builtin_amdgcn_s_barrier();
    compute(0);
    __builtin_amdgcn_s_barrier();
    stage(0, (t + 2) * BK);
    asm volatile("s_waitcnt vmcnt(10)" ::: "memory");
    __builtin_amdgcn_s_barrier();
    compute(1);
    __builtin_amdgcn_s_barrier();
  }
  asm volatile("s_waitcnt vmcnt(0)" ::: "memory");
  __builtin_amdgcn_s_barrier();
  compute(0);

#pragma unroll
  for (int mf = 0; mf < 4; ++mf)
#pragma unroll
    for (int r = 0; r < 4; ++r) {
      int slot = m0 + msub + mf * 16 + l4 * 4 + r;
      if (slot < cnt) {
        int tok = mylst[slot];
#pragma unroll
        for (int nf = 0; nf < 6; ++nf) {
          int col = n0 + nsub + nf * 16 + l15;
          atomicAdd(out + (size_t)tok * HDIM + col, acc[mf][nf][r]);
        }
      }
    }
}

// ---------------- launcher ----------------
extern "C" void kernel_launch(void* const* d_in, const int* in_sizes, int n_in,
                              void* d_out, int out_size, void* d_ws, size_t ws_size,
                              hipStream_t stream) {
  (void)in_sizes; (void)n_in;
  const float* x  = (const float*)d_in[0];
  const float* rw = (const float*)d_in[1];
  const float* rb = (const float*)d_in[2];
  const float* wg = (const float*)d_in[3];
  const float* wu = (const float*)d_in[4];
  const float* wd = (const float*)d_in[5];
  float* out = (float*)d_out;

  char* ws = (char*)d_ws;
  float* aff     = (float*)ws;                     // 131072 B
  int*   cnt     = (int*)(ws + 131072);            // 512 B
  int*   lst     = (int*)(ws + 131584);            // 131072 B
  int*   gbs_gu  = (int*)(ws + 262656);            // 64 B
  int*   gbs_dn  = (int*)(ws + 262720);            // 64 B
  int*   ess     = (int*)(ws + 262784);            // 64 B
  int*   gtot_gu = (int*)(ws + 262848);            // 64 B
  int*   gtot_dn = (int*)(ws + 262912);            // 64 B
  unsigned short* xb = (unsigned short*)(ws + 263168);   // 23,592,960 B
  const size_t OFF_H4 = 263168 + 23592960ull;

  const size_t WELB = (size_t)WEL * 2;
  int G = 1;
  {
    size_t need8 = OFF_H4 + (size_t)16384 * IDIM * 2 + 8 * 3 * WELB;
    size_t need2 = OFF_H4 + (size_t)8192  * IDIM * 2 + 2 * 3 * WELB;
    if (ws_size >= need8) G = 8;
    else if (ws_size >= need2) G = 2;
  }
  const size_t h4b = (size_t)((G == 8) ? 16384 : (G == 2 ? 8192 : 4096)) * IDIM * 2;
  unsigned short* h4   = (unsigned short*)(ws + OFF_H4);
  unsigned short* wbuf = (unsigned short*)(ws + OFF_H4 + h4b);

  const int NG = NEXP / G;
  const int NBLK_GU = (T_TOK * TOPK / BM + NEXP) * NPAN_GU;  // worst-case
  const int NBLK_DN = (T_TOK * TOPK / BM + NEXP) * NPAN_DN;

  hipMemsetAsync(out, 0, (size_t)out_size * sizeof(float), stream);
  hipMemsetAsync(cnt, 0, 512, stream);
  router_kernel<<<T_TOK / 16, 256, 0, stream>>>(x, rw, rb, aff, cnt, lst, xb);
  sched_kernel<<<1, 64, 0, stream>>>(cnt, gbs_gu, gbs_dn, ess, gtot_gu, gtot_dn, G);

  for (int g = 0; g < NG; ++g) {
    int ge = g * G;
    transpose_group_kernel<<<dim3(45, 45, 3 * G), 256, 0, stream>>>(wg, wu, wd, wbuf, ge);
    gateup_kernel<<<NBLK_GU, 256, 0, stream>>>(
        xb, wbuf, aff, lst, cnt, gbs_gu, ess, gtot_gu + g, h4, ge, G);
    down_kernel<<<NBLK_DN, 256, 0, stream>>>(
        h4, wbuf, out, lst, cnt, gbs_dn, ess, gtot_dn + g, ge, G);
  }
}